// Round 1
// baseline (1724.394 us; speedup 1.0000x reference)
//
#include <hip/hip_runtime.h>
#include <math.h>

#define BATCH 2
#define SEQ   2048
#define DIM   1024
#define NH    16
#define HD    64
#define M_TOT (BATCH*SEQ)   // 4096

// ---------------------------------------------------------------------------
// C = A(MxK) * W(NxK)^T    (both row-major, K contiguous)  K = DIM = 1024
// MODE 0: scatter output into [B, H, T, HD]   (N-tile of 64 == one head)
// MODE 1: plain row-major [M, N] output + bias
// Tile 64x64, BK=32, 256 threads, 4x4 acc/thread.
// LDS is unpadded; 16B chunk index XOR-swizzled with (row>>2) to keep
// the stride-4-row ds_read_b128 patterns at <=2-way bank conflict.
// ---------------------------------------------------------------------------
template<int MODE>
__global__ __launch_bounds__(256)
void gemm_nt(const float* __restrict__ A, const float* __restrict__ W,
             const float* __restrict__ bias, float* __restrict__ C)
{
    const int K = DIM;
    __shared__ float As[64][32];
    __shared__ float Ws[64][32];
    const int tid = threadIdx.x;
    const int tx = tid & 15, ty = tid >> 4;
    const int brow = blockIdx.x * 64;
    const int bcol = blockIdx.y * 64;

    float acc[4][4] = {};

    for (int kt = 0; kt < K; kt += 32) {
        __syncthreads();
        #pragma unroll
        for (int s = tid; s < 512; s += 256) {
            int r  = s >> 3, c4 = s & 7;
            int cs = ((c4 ^ (r >> 2)) & 7) * 4;
            float4 av = *(const float4*)&A[(size_t)(brow + r) * K + kt + c4 * 4];
            *(float4*)&As[r][cs] = av;
            float4 wv = *(const float4*)&W[(size_t)(bcol + r) * K + kt + c4 * 4];
            *(float4*)&Ws[r][cs] = wv;
        }
        __syncthreads();
        #pragma unroll
        for (int c4 = 0; c4 < 8; ++c4) {
            float4 a4[4], w4[4];
            #pragma unroll
            for (int i = 0; i < 4; ++i)
                a4[i] = *(const float4*)&As[ty*4+i][((c4 ^ ty) & 7) * 4];
            #pragma unroll
            for (int j = 0; j < 4; ++j)
                w4[j] = *(const float4*)&Ws[tx*4+j][((c4 ^ tx) & 7) * 4];
            #pragma unroll
            for (int i = 0; i < 4; ++i)
                #pragma unroll
                for (int j = 0; j < 4; ++j)
                    acc[i][j] += a4[i].x*w4[j].x + a4[i].y*w4[j].y
                               + a4[i].z*w4[j].z + a4[i].w*w4[j].w;
        }
    }

    if (MODE == 0) {
        const int h = blockIdx.y;   // N-tile == head
        #pragma unroll
        for (int i = 0; i < 4; ++i) {
            int row = brow + ty*4 + i;          // [0, 4096)
            int b = row >> 11, t = row & (SEQ - 1);
            float4 o = make_float4(acc[i][0], acc[i][1], acc[i][2], acc[i][3]);
            *(float4*)&C[(((size_t)(b*NH + h)*SEQ + t) << 6) + tx*4] = o;
        }
    } else {
        #pragma unroll
        for (int i = 0; i < 4; ++i) {
            int row = brow + ty*4 + i;
            int col = bcol + tx*4;
            float4 bb = *(const float4*)&bias[col];
            float4 o = make_float4(acc[i][0]+bb.x, acc[i][1]+bb.y,
                                   acc[i][2]+bb.z, acc[i][3]+bb.w);
            *(float4*)&C[(size_t)row * DIM + col] = o;
        }
    }
}

// ---------------------------------------------------------------------------
// Flash attention (causal), fp32. One block = 64 q-rows of one (b,h).
// Online softmax; VsT holds V transposed so PV is a row-dot like QK^T.
// ---------------------------------------------------------------------------
__global__ __launch_bounds__(256)
void attn_fwd(const float* __restrict__ q, const float* __restrict__ k,
              const float* __restrict__ v, float* __restrict__ ctx)
{
    __shared__ float Qs[64][64];
    __shared__ float Ks[64][64];
    __shared__ float VsT[64][64];
    __shared__ float Ps[64][64];

    const int tid = threadIdx.x;
    const int tx = tid & 15, ty = tid >> 4;
    const int qb = blockIdx.x;          // q tile, 0..31
    const int bh = blockIdx.y;          // b*H+h, 0..31
    const float* Qg = q + (size_t)bh * SEQ * HD + (size_t)qb * 64 * HD;
    const float* Kg = k + (size_t)bh * SEQ * HD;
    const float* Vg = v + (size_t)bh * SEQ * HD;

    // stage Q tile (64x64), swizzled
    #pragma unroll
    for (int s = tid; s < 1024; s += 256) {
        int r = s >> 4, c4 = s & 15;
        float4 val = *(const float4*)&Qg[r * HD + c4 * 4];
        *(float4*)&Qs[r][((c4 ^ (r >> 2)) & 15) * 4] = val;
    }

    float m_[4], l_[4], acc[4][4] = {};
    #pragma unroll
    for (int i = 0; i < 4; ++i) { m_[i] = -INFINITY; l_[i] = 0.f; }

    const int nkt = qb + 1;
    for (int kt = 0; kt < nkt; ++kt) {
        __syncthreads();    // prev PV done before K/V overwrite (publishes Qs on iter 0)
        #pragma unroll
        for (int s = tid; s < 1024; s += 256) {
            int r = s >> 4, c4 = s & 15;
            float4 kv = *(const float4*)&Kg[(size_t)(kt*64 + r) * HD + c4 * 4];
            *(float4*)&Ks[r][((c4 ^ (r >> 2)) & 15) * 4] = kv;
            float4 vv = *(const float4*)&Vg[(size_t)(kt*64 + r) * HD + c4 * 4];
            int rc = r >> 2, re = r & 3;
            VsT[c4*4+0][((rc ^ (c4)) & 15) * 4 + re] = vv.x;   // row c4*4+0 key = c4
            VsT[c4*4+1][((rc ^ (c4)) & 15) * 4 + re] = vv.y;
            VsT[c4*4+2][((rc ^ (c4)) & 15) * 4 + re] = vv.z;
            VsT[c4*4+3][((rc ^ (c4)) & 15) * 4 + re] = vv.w;
        }
        __syncthreads();

        // S = Q K^T (4x4 per thread)
        float s4[4][4] = {};
        #pragma unroll
        for (int c4 = 0; c4 < 16; ++c4) {
            float4 a4[4], b4[4];
            #pragma unroll
            for (int i = 0; i < 4; ++i)
                a4[i] = *(const float4*)&Qs[ty*4+i][((c4 ^ ty) & 15) * 4];
            #pragma unroll
            for (int j = 0; j < 4; ++j)
                b4[j] = *(const float4*)&Ks[tx*4+j][((c4 ^ tx) & 15) * 4];
            #pragma unroll
            for (int i = 0; i < 4; ++i)
                #pragma unroll
                for (int j = 0; j < 4; ++j)
                    s4[i][j] += a4[i].x*b4[j].x + a4[i].y*b4[j].y
                              + a4[i].z*b4[j].z + a4[i].w*b4[j].w;
        }

        const float scale = 0.125f;     // 1/sqrt(64)
        const bool diag = (kt == qb);
        float p[4][4];
        #pragma unroll
        for (int i = 0; i < 4; ++i) {
            float mt = -INFINITY;
            #pragma unroll
            for (int j = 0; j < 4; ++j) {
                float sv = s4[i][j] * scale;
                if (diag && (tx*4+j) > (ty*4+i)) sv = -INFINITY;
                s4[i][j] = sv;
                mt = fmaxf(mt, sv);
            }
            #pragma unroll
            for (int off = 1; off < 16; off <<= 1)
                mt = fmaxf(mt, __shfl_xor(mt, off));
            float mnew = fmaxf(m_[i], mt);
            float sc = __expf(m_[i] - mnew);
            float lt = 0.f;
            #pragma unroll
            for (int j = 0; j < 4; ++j) {
                float pv = __expf(s4[i][j] - mnew);
                p[i][j] = pv;
                lt += pv;
            }
            #pragma unroll
            for (int off = 1; off < 16; off <<= 1)
                lt += __shfl_xor(lt, off);
            l_[i] = l_[i] * sc + lt;
            m_[i] = mnew;
            #pragma unroll
            for (int j = 0; j < 4; ++j) acc[i][j] *= sc;
        }

        // publish P tile (each thread owns cols tx*4..tx*4+3 of its 4 rows)
        #pragma unroll
        for (int i = 0; i < 4; ++i)
            *(float4*)&Ps[ty*4+i][((tx ^ ty) & 15) * 4] =
                make_float4(p[i][0], p[i][1], p[i][2], p[i][3]);
        __syncthreads();

        // O += P * V
        #pragma unroll
        for (int c4 = 0; c4 < 16; ++c4) {
            float4 p4[4], v4[4];
            #pragma unroll
            for (int i = 0; i < 4; ++i)
                p4[i] = *(const float4*)&Ps[ty*4+i][((c4 ^ ty) & 15) * 4];
            #pragma unroll
            for (int j = 0; j < 4; ++j)
                v4[j] = *(const float4*)&VsT[tx*4+j][((c4 ^ tx) & 15) * 4];
            #pragma unroll
            for (int i = 0; i < 4; ++i)
                #pragma unroll
                for (int j = 0; j < 4; ++j)
                    acc[i][j] += p4[i].x*v4[j].x + p4[i].y*v4[j].y
                               + p4[i].z*v4[j].z + p4[i].w*v4[j].w;
        }
    }

    float* Cg = ctx + (size_t)bh * SEQ * HD + (size_t)qb * 64 * HD;
    #pragma unroll
    for (int i = 0; i < 4; ++i) {
        float inv = 1.f / l_[i];
        *(float4*)&Cg[(ty*4+i) * HD + tx*4] =
            make_float4(acc[i][0]*inv, acc[i][1]*inv, acc[i][2]*inv, acc[i][3]*inv);
    }
}

// ---------------------------------------------------------------------------
extern "C" void kernel_launch(void* const* d_in, const int* in_sizes, int n_in,
                              void* d_out, int out_size, void* d_ws, size_t ws_size,
                              hipStream_t stream)
{
    (void)in_sizes; (void)n_in; (void)out_size; (void)ws_size;
    const float* x  = (const float*)d_in[0];
    const float* Wq = (const float*)d_in[1];
    const float* Wk = (const float*)d_in[2];
    const float* Wv = (const float*)d_in[3];
    const float* Wo = (const float*)d_in[4];
    const float* bo = (const float*)d_in[5];
    float* out = (float*)d_out;

    float* ws   = (float*)d_ws;
    float* qb   = ws;                           // [B,H,T,HD] 4M floats
    float* kb   = ws + (size_t)4194304;
    float* vb   = ws + (size_t)8388608;
    float* ctxb = ws + (size_t)12582912;        // flat == [B*T, D] for out-proj

    dim3 gg(M_TOT/64, DIM/64);
    gemm_nt<0><<<gg, 256, 0, stream>>>(x, Wq, nullptr, qb);
    gemm_nt<0><<<gg, 256, 0, stream>>>(x, Wk, nullptr, kb);
    gemm_nt<0><<<gg, 256, 0, stream>>>(x, Wv, nullptr, vb);

    dim3 ga(SEQ/64, BATCH*NH);
    attn_fwd<<<ga, 256, 0, stream>>>(qb, kb, vb, ctxb);

    gemm_nt<1><<<gg, 256, 0, stream>>>(ctxb, Wo, bo, out);
}

// Round 2
// 340.216 us; speedup vs baseline: 5.0685x; 5.0685x over previous
//
#include <hip/hip_runtime.h>
#include <math.h>

#define BATCH 2
#define SEQ   2048
#define DIM   1024
#define NH    16
#define HD    64
#define MTOT  4096

typedef __attribute__((ext_vector_type(8))) short bf16x8;
typedef __attribute__((ext_vector_type(4))) float f32x4;

__device__ __forceinline__ ushort f2bf(float f) {
    union { float f; unsigned u; } v; v.f = f;
    unsigned r = v.u + 0x7fffu + ((v.u >> 16) & 1u);
    return (ushort)(r >> 16);
}

// ---------------------------------------------------------------------------
// casts
// ---------------------------------------------------------------------------
__global__ __launch_bounds__(256)
void cast_x_k(const float* __restrict__ s, ushort* __restrict__ d, int n4)
{
    for (int i = blockIdx.x * blockDim.x + threadIdx.x; i < n4;
         i += gridDim.x * blockDim.x) {
        float4 v = ((const float4*)s)[i];
        ushort4 o;
        o.x = f2bf(v.x); o.y = f2bf(v.y); o.z = f2bf(v.z); o.w = f2bf(v.w);
        ((ushort4*)d)[i] = o;
    }
}

__global__ __launch_bounds__(256)
void cast_w_k(const float* __restrict__ s0, const float* __restrict__ s1,
              const float* __restrict__ s2, const float* __restrict__ s3,
              ushort* __restrict__ d0, ushort* __restrict__ d1,
              ushort* __restrict__ d2, ushort* __restrict__ d3, int n4)
{
    const float* s = (blockIdx.y == 0) ? s0 : (blockIdx.y == 1) ? s1
                   : (blockIdx.y == 2) ? s2 : s3;
    ushort* d = (blockIdx.y == 0) ? d0 : (blockIdx.y == 1) ? d1
              : (blockIdx.y == 2) ? d2 : d3;
    for (int i = blockIdx.x * blockDim.x + threadIdx.x; i < n4;
         i += gridDim.x * blockDim.x) {
        float4 v = ((const float4*)s)[i];
        ushort4 o;
        o.x = f2bf(v.x); o.y = f2bf(v.y); o.z = f2bf(v.z); o.w = f2bf(v.w);
        ((ushort4*)d)[i] = o;
    }
}

// ---------------------------------------------------------------------------
// bf16 NT GEMM:  C = A(MxK) * W(NxK)^T, K = 1024. 128x128 tile, BK=64,
// 256 thr (4 waves, 2x2), each wave 64x64 via 4x4 mfma_16x16x32 frags.
// MODE 0: bf16 scatter to [B,H,T,HD]; grid.z selects (W,Dst) among Q/K/V.
// MODE 1: fp32 [M,N] + bias.
// LDS rows = 8 x 16B chunks, chunk idx XOR (row&7) -> 2-way conflicts (free).
// ---------------------------------------------------------------------------
template<int MODE>
__global__ __launch_bounds__(256)
void gemm_bf16(const ushort* __restrict__ A,
               const ushort* __restrict__ W0, const ushort* __restrict__ W1,
               const ushort* __restrict__ W2,
               ushort* __restrict__ D0, ushort* __restrict__ D1,
               ushort* __restrict__ D2,
               const float* __restrict__ bias, float* __restrict__ Fout)
{
    __shared__ __align__(16) ushort As[128 * 64];
    __shared__ __align__(16) ushort Bs[128 * 64];

    const int tid = threadIdx.x;
    const int w = tid >> 6, l = tid & 63;
    const int g = l >> 4, l15 = l & 15;
    const int wr = w >> 1, wc = w & 1;
    const int brow = blockIdx.x * 128, bcol = blockIdx.y * 128;

    const ushort* W = (MODE == 1) ? W0
                    : (blockIdx.z == 0 ? W0 : (blockIdx.z == 1 ? W1 : W2));
    ushort* Dst = (MODE == 1) ? (ushort*)0
                : (blockIdx.z == 0 ? D0 : (blockIdx.z == 1 ? D1 : D2));

    int4 ra[4], rb[4];
    #pragma unroll
    for (int i = 0; i < 4; ++i) {
        int c = tid + 256 * i;
        int row = c >> 3, cc = c & 7;
        ra[i] = *(const int4*)&A[(size_t)(brow + row) * DIM + cc * 8];
        rb[i] = *(const int4*)&W[(size_t)(bcol + row) * DIM + cc * 8];
    }

    f32x4 acc[4][4] = {};

    for (int kt = 0; kt < DIM; kt += 64) {
        __syncthreads();
        #pragma unroll
        for (int i = 0; i < 4; ++i) {
            int c = tid + 256 * i;
            int row = c >> 3, cc = c & 7;
            *(int4*)&As[row * 64 + ((cc ^ (row & 7)) * 8)] = ra[i];
            *(int4*)&Bs[row * 64 + ((cc ^ (row & 7)) * 8)] = rb[i];
        }
        __syncthreads();
        if (kt + 64 < DIM) {
            #pragma unroll
            for (int i = 0; i < 4; ++i) {
                int c = tid + 256 * i;
                int row = c >> 3, cc = c & 7;
                ra[i] = *(const int4*)&A[(size_t)(brow + row) * DIM + kt + 64 + cc * 8];
                rb[i] = *(const int4*)&W[(size_t)(bcol + row) * DIM + kt + 64 + cc * 8];
            }
        }
        #pragma unroll
        for (int kh = 0; kh < 2; ++kh) {
            bf16x8 af[4], bfr[4];
            #pragma unroll
            for (int mi = 0; mi < 4; ++mi) {
                int row = 64 * wr + 16 * mi + l15;
                af[mi] = *(const bf16x8*)&As[row * 64 + (((4 * kh + g) ^ (row & 7)) * 8)];
            }
            #pragma unroll
            for (int nj = 0; nj < 4; ++nj) {
                int row = 64 * wc + 16 * nj + l15;
                bfr[nj] = *(const bf16x8*)&Bs[row * 64 + (((4 * kh + g) ^ (row & 7)) * 8)];
            }
            #pragma unroll
            for (int mi = 0; mi < 4; ++mi)
                #pragma unroll
                for (int nj = 0; nj < 4; ++nj)
                    acc[mi][nj] = __builtin_amdgcn_mfma_f32_16x16x32_bf16(
                        af[mi], bfr[nj], acc[mi][nj], 0, 0, 0);
        }
    }

    if (MODE == 0) {
        #pragma unroll
        for (int mi = 0; mi < 4; ++mi)
            #pragma unroll
            for (int nj = 0; nj < 4; ++nj)
                #pragma unroll
                for (int reg = 0; reg < 4; ++reg) {
                    int row = brow + 64 * wr + 16 * mi + 4 * g + reg;
                    int col = bcol + 64 * wc + 16 * nj + l15;
                    int b = row >> 11, t = row & (SEQ - 1);
                    int h = col >> 6, hd = col & 63;
                    Dst[((size_t)(b * NH + h) * SEQ + t) * HD + hd] =
                        f2bf(acc[mi][nj][reg]);
                }
    } else {
        #pragma unroll
        for (int nj = 0; nj < 4; ++nj) {
            int col = bcol + 64 * wc + 16 * nj + l15;
            float bv = bias[col];
            #pragma unroll
            for (int mi = 0; mi < 4; ++mi)
                #pragma unroll
                for (int reg = 0; reg < 4; ++reg) {
                    int row = brow + 64 * wr + 16 * mi + 4 * g + reg;
                    Fout[(size_t)row * DIM + col] = acc[mi][nj][reg] + bv;
                }
        }
    }
}

// ---------------------------------------------------------------------------
// MFMA flash attention (causal). Block = 64 q-rows of one (b,h), 4 waves,
// wave w owns q-strip 16w..16w+15. KV tile 64. S,P,O via 16x16x32 MFMA.
// P converted C-layout -> A-layout via wave-local swizzled LDS round-trip.
// V transposed into LDS at staging so PV B-frag is a contiguous row read.
// ---------------------------------------------------------------------------
__global__ __launch_bounds__(256)
void attn_mfma(const ushort* __restrict__ q, const ushort* __restrict__ k,
               const ushort* __restrict__ v, ushort* __restrict__ ctx)
{
    __shared__ __align__(16) ushort Qs[64 * 64];
    __shared__ __align__(16) ushort Ks[64 * 64];
    __shared__ __align__(16) ushort Vt[64 * 64];
    __shared__ __align__(16) ushort Ps[64 * 64];

    const int tid = threadIdx.x;
    const int w = tid >> 6, l = tid & 63;
    const int g = l >> 4, l15 = l & 15;
    const int qb = blockIdx.x, bh = blockIdx.y;

    const ushort* Qg = q + (size_t)bh * SEQ * HD + (size_t)qb * 64 * HD;
    const ushort* Kg = k + (size_t)bh * SEQ * HD;
    const ushort* Vg = v + (size_t)bh * SEQ * HD;

    int4 rq[2], rk[2], rv[2];
    #pragma unroll
    for (int i = 0; i < 2; ++i) {
        int c = tid + 256 * i;
        int row = c >> 3, cc = c & 7;
        rq[i] = *(const int4*)&Qg[row * HD + cc * 8];
        rk[i] = *(const int4*)&Kg[row * HD + cc * 8];
        rv[i] = *(const int4*)&Vg[row * HD + cc * 8];
    }
    #pragma unroll
    for (int i = 0; i < 2; ++i) {
        int c = tid + 256 * i;
        int row = c >> 3, cc = c & 7;
        *(int4*)&Qs[row * 64 + ((cc ^ (row & 7)) * 8)] = rq[i];
    }

    f32x4 o[4] = {};
    float m_[4], l_[4];
    #pragma unroll
    for (int i = 0; i < 4; ++i) { m_[i] = -INFINITY; l_[i] = 0.f; }
    bf16x8 aq[2];

    for (int kt = 0; kt <= qb; ++kt) {
        __syncthreads();                 // prev-iter reads of Ks/Vt done
        #pragma unroll
        for (int i = 0; i < 2; ++i) {
            int c = tid + 256 * i;
            int row = c >> 3, cc = c & 7;
            *(int4*)&Ks[row * 64 + ((cc ^ (row & 7)) * 8)] = rk[i];
            union { int4 v4; ushort u[8]; } uv; uv.v4 = rv[i];
            #pragma unroll
            for (int e = 0; e < 8; ++e) {
                int d = 8 * cc + e;
                Vt[d * 64 + (((row >> 3) ^ e) * 8) + (row & 7)] = uv.u[e];
            }
        }
        __syncthreads();
        if (kt == 0) {
            #pragma unroll
            for (int kh = 0; kh < 2; ++kh) {
                int row = 16 * w + l15;
                aq[kh] = *(const bf16x8*)&Qs[row * 64 + (((4 * kh + g) ^ (row & 7)) * 8)];
            }
        }
        if (kt < qb) {                   // prefetch next K/V tile (T14)
            #pragma unroll
            for (int i = 0; i < 2; ++i) {
                int c = tid + 256 * i;
                int row = c >> 3, cc = c & 7;
                rk[i] = *(const int4*)&Kg[(size_t)(kt + 1) * 64 * HD + row * HD + cc * 8];
                rv[i] = *(const int4*)&Vg[(size_t)(kt + 1) * 64 * HD + row * HD + cc * 8];
            }
        }

        // S = Q K^T
        f32x4 s[4] = {};
        #pragma unroll
        for (int kh = 0; kh < 2; ++kh)
            #pragma unroll
            for (int f = 0; f < 4; ++f) {
                int row = 16 * f + l15;
                bf16x8 bk = *(const bf16x8*)&Ks[row * 64 + (((4 * kh + g) ^ (row & 7)) * 8)];
                s[f] = __builtin_amdgcn_mfma_f32_16x16x32_bf16(aq[kh], bk, s[f], 0, 0, 0);
            }

        // online softmax (rows live in regs: row = 16w+4g+reg, col = 16f+l15)
        const bool diag = (kt == qb);
        #pragma unroll
        for (int reg = 0; reg < 4; ++reg) {
            int qp = 16 * w + 4 * g + reg;
            float mt = -INFINITY;
            #pragma unroll
            for (int f = 0; f < 4; ++f) {
                float sv = s[f][reg] * 0.125f;
                if (diag && (16 * f + l15) > qp) sv = -INFINITY;
                s[f][reg] = sv;
                mt = fmaxf(mt, sv);
            }
            mt = fmaxf(mt, __shfl_xor(mt, 1));
            mt = fmaxf(mt, __shfl_xor(mt, 2));
            mt = fmaxf(mt, __shfl_xor(mt, 4));
            mt = fmaxf(mt, __shfl_xor(mt, 8));
            float mnew = fmaxf(m_[reg], mt);
            float sc = __expf(m_[reg] - mnew);
            float lt = 0.f;
            #pragma unroll
            for (int f = 0; f < 4; ++f) {
                float pv = __expf(s[f][reg] - mnew);
                s[f][reg] = pv;
                lt += pv;
            }
            lt += __shfl_xor(lt, 1);
            lt += __shfl_xor(lt, 2);
            lt += __shfl_xor(lt, 4);
            lt += __shfl_xor(lt, 8);
            l_[reg] = l_[reg] * sc + lt;
            m_[reg] = mnew;
            #pragma unroll
            for (int nj = 0; nj < 4; ++nj) o[nj][reg] *= sc;
        }

        // P (C-layout regs) -> wave-local LDS (A-layout readable)
        #pragma unroll
        for (int f = 0; f < 4; ++f)
            #pragma unroll
            for (int reg = 0; reg < 4; ++reg) {
                int qp = 16 * w + 4 * g + reg;
                int kvc = 16 * f + l15;
                Ps[qp * 64 + (((kvc >> 3) ^ (qp & 7)) * 8) + (kvc & 7)] = f2bf(s[f][reg]);
            }
        asm volatile("s_waitcnt lgkmcnt(0)" ::: "memory");  // wave-local publish

        // O += P V
        #pragma unroll
        for (int kb = 0; kb < 2; ++kb) {
            int prow = 16 * w + l15;
            bf16x8 ap = *(const bf16x8*)&Ps[prow * 64 + (((4 * kb + g) ^ (prow & 7)) * 8)];
            #pragma unroll
            for (int nj = 0; nj < 4; ++nj) {
                int d = 16 * nj + l15;
                bf16x8 bv = *(const bf16x8*)&Vt[d * 64 + (((4 * kb + g) ^ (d & 7)) * 8)];
                o[nj] = __builtin_amdgcn_mfma_f32_16x16x32_bf16(ap, bv, o[nj], 0, 0, 0);
            }
        }
    }

    #pragma unroll
    for (int reg = 0; reg < 4; ++reg) {
        int qp = 16 * w + 4 * g + reg;
        float inv = 1.f / l_[reg];
        #pragma unroll
        for (int nj = 0; nj < 4; ++nj)
            ctx[(size_t)bh * SEQ * HD + (size_t)(qb * 64 + qp) * HD + 16 * nj + l15] =
                f2bf(o[nj][reg] * inv);
    }
}

// ---------------------------------------------------------------------------
extern "C" void kernel_launch(void* const* d_in, const int* in_sizes, int n_in,
                              void* d_out, int out_size, void* d_ws, size_t ws_size,
                              hipStream_t stream)
{
    (void)in_sizes; (void)n_in; (void)out_size; (void)ws_size;
    const float* x  = (const float*)d_in[0];
    const float* Wq = (const float*)d_in[1];
    const float* Wk = (const float*)d_in[2];
    const float* Wv = (const float*)d_in[3];
    const float* Wo = (const float*)d_in[4];
    const float* bo = (const float*)d_in[5];
    float* out = (float*)d_out;

    ushort* wsu  = (ushort*)d_ws;
    ushort* xb   = wsu;                      // 4M
    ushort* wqb  = wsu + 4194304;            // 1M
    ushort* wkb  = wsu + 5242880;
    ushort* wvb  = wsu + 6291456;
    ushort* wob  = wsu + 7340032;
    ushort* qbuf = wsu + 8388608;            // 4M each, [B,H,T,HD]
    ushort* kbuf = wsu + 12582912;
    ushort* vbuf = wsu + 16777216;
    ushort* ctxb = wsu + 20971520;           // 4M, flat == [B*T, D]

    cast_x_k<<<2048, 256, 0, stream>>>(x, xb, MTOT * DIM / 4);
    cast_w_k<<<dim3(512, 4), 256, 0, stream>>>(Wq, Wk, Wv, Wo,
                                               wqb, wkb, wvb, wob, DIM * DIM / 4);

    dim3 gqkv(MTOT / 128, DIM / 128, 3);
    gemm_bf16<0><<<gqkv, 256, 0, stream>>>(xb, wqb, wkb, wvb,
                                           qbuf, kbuf, vbuf, nullptr, nullptr);

    dim3 ga(SEQ / 64, BATCH * NH);
    attn_mfma<<<ga, 256, 0, stream>>>(qbuf, kbuf, vbuf, ctxb);

    dim3 go(MTOT / 128, DIM / 128, 1);
    gemm_bf16<1><<<go, 256, 0, stream>>>(ctxb, wob, nullptr, nullptr,
                                         nullptr, nullptr, nullptr, bo, out);
}

// Round 3
// 281.714 us; speedup vs baseline: 6.1211x; 1.2077x over previous
//
#include <hip/hip_runtime.h>
#include <math.h>

#define BATCH 2
#define SEQ   2048
#define DIM   1024
#define NH    16
#define HD    64
#define MTOT  4096

typedef __attribute__((ext_vector_type(8)))  short bf16x8;
typedef __attribute__((ext_vector_type(4)))  float f32x4;
typedef __attribute__((ext_vector_type(16))) float f32x16;

__device__ __forceinline__ ushort f2bf(float f) {
    union { float f; unsigned u; } v; v.f = f;
    unsigned r = v.u + 0x7fffu + ((v.u >> 16) & 1u);
    return (ushort)(r >> 16);
}

__device__ __forceinline__ unsigned cvtpk_bf16(float lo, float hi) {
    unsigned r;
    asm("v_cvt_pk_bf16_f32 %0, %1, %2" : "=v"(r) : "v"(lo), "v"(hi));
    return r;
}

// ---------------------------------------------------------------------------
// casts
// ---------------------------------------------------------------------------
__global__ __launch_bounds__(256)
void cast_x_k(const float* __restrict__ s, ushort* __restrict__ d, int n4)
{
    for (int i = blockIdx.x * blockDim.x + threadIdx.x; i < n4;
         i += gridDim.x * blockDim.x) {
        float4 v = ((const float4*)s)[i];
        ushort4 o;
        o.x = f2bf(v.x); o.y = f2bf(v.y); o.z = f2bf(v.z); o.w = f2bf(v.w);
        ((ushort4*)d)[i] = o;
    }
}

__global__ __launch_bounds__(256)
void cast_w_k(const float* __restrict__ s0, const float* __restrict__ s1,
              const float* __restrict__ s2, const float* __restrict__ s3,
              ushort* __restrict__ d0, ushort* __restrict__ d1,
              ushort* __restrict__ d2, ushort* __restrict__ d3, int n4)
{
    const float* s = (blockIdx.y == 0) ? s0 : (blockIdx.y == 1) ? s1
                   : (blockIdx.y == 2) ? s2 : s3;
    ushort* d = (blockIdx.y == 0) ? d0 : (blockIdx.y == 1) ? d1
              : (blockIdx.y == 2) ? d2 : d3;
    for (int i = blockIdx.x * blockDim.x + threadIdx.x; i < n4;
         i += gridDim.x * blockDim.x) {
        float4 v = ((const float4*)s)[i];
        ushort4 o;
        o.x = f2bf(v.x); o.y = f2bf(v.y); o.z = f2bf(v.z); o.w = f2bf(v.w);
        ((ushort4*)d)[i] = o;
    }
}

// ---------------------------------------------------------------------------
// bf16 NT GEMM:  C = A(MxK) * W(NxK)^T, K = 1024. 128x128 tile, BK=64.
// MODE 0: bf16 scatter; z=0 -> Q*(0.125) into [B,H,T,HD]; z=1 -> K into
//         [B,H,T,HD]; z=2 -> V transposed into [B,H,HD,T].
// MODE 1: fp32 [M,N] + bias.
// ---------------------------------------------------------------------------
template<int MODE>
__global__ __launch_bounds__(256)
void gemm_bf16(const ushort* __restrict__ A,
               const ushort* __restrict__ W0, const ushort* __restrict__ W1,
               const ushort* __restrict__ W2,
               ushort* __restrict__ D0, ushort* __restrict__ D1,
               ushort* __restrict__ D2,
               const float* __restrict__ bias, float* __restrict__ Fout)
{
    __shared__ __align__(16) ushort As[128 * 64];
    __shared__ __align__(16) ushort Bs[128 * 64];

    const int tid = threadIdx.x;
    const int w = tid >> 6, l = tid & 63;
    const int g = l >> 4, l15 = l & 15;
    const int wr = w >> 1, wc = w & 1;
    const int brow = blockIdx.x * 128, bcol = blockIdx.y * 128;

    const ushort* W = (MODE == 1) ? W0
                    : (blockIdx.z == 0 ? W0 : (blockIdx.z == 1 ? W1 : W2));
    ushort* Dst = (MODE == 1) ? (ushort*)0
                : (blockIdx.z == 0 ? D0 : (blockIdx.z == 1 ? D1 : D2));

    int4 ra[4], rb[4];
    #pragma unroll
    for (int i = 0; i < 4; ++i) {
        int c = tid + 256 * i;
        int row = c >> 3, cc = c & 7;
        ra[i] = *(const int4*)&A[(size_t)(brow + row) * DIM + cc * 8];
        rb[i] = *(const int4*)&W[(size_t)(bcol + row) * DIM + cc * 8];
    }

    f32x4 acc[4][4] = {};

    for (int kt = 0; kt < DIM; kt += 64) {
        __syncthreads();
        #pragma unroll
        for (int i = 0; i < 4; ++i) {
            int c = tid + 256 * i;
            int row = c >> 3, cc = c & 7;
            *(int4*)&As[row * 64 + ((cc ^ (row & 7)) * 8)] = ra[i];
            *(int4*)&Bs[row * 64 + ((cc ^ (row & 7)) * 8)] = rb[i];
        }
        __syncthreads();
        if (kt + 64 < DIM) {
            #pragma unroll
            for (int i = 0; i < 4; ++i) {
                int c = tid + 256 * i;
                int row = c >> 3, cc = c & 7;
                ra[i] = *(const int4*)&A[(size_t)(brow + row) * DIM + kt + 64 + cc * 8];
                rb[i] = *(const int4*)&W[(size_t)(bcol + row) * DIM + kt + 64 + cc * 8];
            }
        }
        #pragma unroll
        for (int kh = 0; kh < 2; ++kh) {
            bf16x8 af[4], bfr[4];
            #pragma unroll
            for (int mi = 0; mi < 4; ++mi) {
                int row = 64 * wr + 16 * mi + l15;
                af[mi] = *(const bf16x8*)&As[row * 64 + (((4 * kh + g) ^ (row & 7)) * 8)];
            }
            #pragma unroll
            for (int nj = 0; nj < 4; ++nj) {
                int row = 64 * wc + 16 * nj + l15;
                bfr[nj] = *(const bf16x8*)&Bs[row * 64 + (((4 * kh + g) ^ (row & 7)) * 8)];
            }
            #pragma unroll
            for (int mi = 0; mi < 4; ++mi)
                #pragma unroll
                for (int nj = 0; nj < 4; ++nj)
                    acc[mi][nj] = __builtin_amdgcn_mfma_f32_16x16x32_bf16(
                        af[mi], bfr[nj], acc[mi][nj], 0, 0, 0);
        }
    }

    if (MODE == 0) {
        const float osc = (blockIdx.z == 0) ? 0.125f : 1.0f;
        if (blockIdx.z == 2) {
            // V^T: [B,H,HD,T]
            #pragma unroll
            for (int mi = 0; mi < 4; ++mi)
                #pragma unroll
                for (int nj = 0; nj < 4; ++nj)
                    #pragma unroll
                    for (int reg = 0; reg < 4; ++reg) {
                        int row = brow + 64 * wr + 16 * mi + 4 * g + reg;
                        int col = bcol + 64 * wc + 16 * nj + l15;
                        int b = row >> 11, t = row & (SEQ - 1);
                        int hh = col >> 6, hd = col & 63;
                        Dst[((size_t)(b * NH + hh) * HD + hd) * SEQ + t] =
                            f2bf(acc[mi][nj][reg]);
                    }
        } else {
            #pragma unroll
            for (int mi = 0; mi < 4; ++mi)
                #pragma unroll
                for (int nj = 0; nj < 4; ++nj)
                    #pragma unroll
                    for (int reg = 0; reg < 4; ++reg) {
                        int row = brow + 64 * wr + 16 * mi + 4 * g + reg;
                        int col = bcol + 64 * wc + 16 * nj + l15;
                        int b = row >> 11, t = row & (SEQ - 1);
                        int hh = col >> 6, hd = col & 63;
                        Dst[((size_t)(b * NH + hh) * SEQ + t) * HD + hd] =
                            f2bf(acc[mi][nj][reg] * osc);
                    }
        }
    } else {
        #pragma unroll
        for (int nj = 0; nj < 4; ++nj) {
            int col = bcol + 64 * wc + 16 * nj + l15;
            float bv = bias[col];
            #pragma unroll
            for (int mi = 0; mi < 4; ++mi)
                #pragma unroll
                for (int reg = 0; reg < 4; ++reg) {
                    int row = brow + 64 * wr + 16 * mi + 4 * g + reg;
                    Fout[(size_t)row * DIM + col] = acc[mi][nj][reg] + bv;
                }
        }
    }
}

// ---------------------------------------------------------------------------
// Swapped-QK^T MFMA flash attention (causal), 32x32x16.
// Block = 128 q-rows of one (b,h); 4 waves x QBLK=32; KV tile 64.
// S^T = mfma(K, Q): lane owns q = lane&31, 32 scores in regs.
// Softmax in-register (exp2 domain; Q pre-scaled by 0.125; defer-max THR=8).
// P -> PV A-frags via cvt_pk + half-wave exchange. O^T = mfma(V^T, P^T).
// V^T comes pre-transposed from global [B,H,HD,T].
// ---------------------------------------------------------------------------
__global__ __launch_bounds__(256, 2)
void attn_mfma2(const ushort* __restrict__ q, const ushort* __restrict__ k,
                const ushort* __restrict__ vt, ushort* __restrict__ ctx)
{
    __shared__ __align__(16) ushort Kb[2][4096];
    __shared__ __align__(16) ushort Vb[2][4096];

    const int tid = threadIdx.x;
    const int wq = tid >> 6, l = tid & 63;
    const int l31 = l & 31, h = l >> 5;
    const int y = blockIdx.y;
    const int qt = (y & 16) ? (15 - (int)blockIdx.x) : (int)blockIdx.x;  // balance
    const int bh = y;
    const int qlo = qt * 128 + wq * 32;
    const int ktmax = 2 * qt + 1;
    const float LOG2E = 1.44269504f;

    const ushort* Qg = q  + (size_t)bh * SEQ * HD;
    const ushort* Kg = k  + (size_t)bh * SEQ * HD;
    const ushort* Vg = vt + (size_t)bh * HD * SEQ;   // rows d, cols t

    // Q fragments: B-frag per dstep s: Q[qlo+l31][16s + 8h + j]
    bf16x8 qf[4];
    #pragma unroll
    for (int s = 0; s < 4; ++s)
        qf[s] = *(const bf16x8*)&Qg[(size_t)(qlo + l31) * HD + 16 * s + 8 * h];

    int4 rk[2], rv[2];
    #pragma unroll
    for (int i = 0; i < 2; ++i) {                    // tile 0
        int idx = tid + 256 * i;
        int row = idx >> 3, c = idx & 7;
        rk[i] = *(const int4*)&Kg[(size_t)row * HD + c * 8];
        rv[i] = *(const int4*)&Vg[(size_t)row * SEQ + c * 8];
    }

    f32x16 o[2] = {};
    float m = -3.0e38f, lsum = 0.f;

    for (int kt = 0; kt <= ktmax; ++kt) {
        const int p = kt & 1;
        __syncthreads();
        #pragma unroll
        for (int i = 0; i < 2; ++i) {
            int idx = tid + 256 * i;
            int row = idx >> 3, c = idx & 7;
            *(int4*)&Kb[p][row * 64 + ((c ^ (row & 7)) * 8)] = rk[i];
            *(int4*)&Vb[p][row * 64 + ((c ^ (row & 7)) * 8)] = rv[i];
        }
        __syncthreads();
        if (kt < ktmax) {
            #pragma unroll
            for (int i = 0; i < 2; ++i) {
                int idx = tid + 256 * i;
                int row = idx >> 3, c = idx & 7;
                rk[i] = *(const int4*)&Kg[(size_t)(64 * (kt + 1) + row) * HD + c * 8];
                rv[i] = *(const int4*)&Vg[(size_t)row * SEQ + 64 * (kt + 1) + c * 8];
            }
        }

        if (64 * kt < qlo + 32) {        // wave has unmasked work in this tile
            // S^T = K · Q^T
            f32x16 st[2] = {};
            #pragma unroll
            for (int s = 0; s < 4; ++s)
                #pragma unroll
                for (int f = 0; f < 2; ++f) {
                    int row = 32 * f + l31;
                    bf16x8 kf = *(const bf16x8*)&Kb[p][row * 64 + (((2 * s + h) ^ (row & 7)) * 8)];
                    st[f] = __builtin_amdgcn_mfma_f32_32x32x16_bf16(kf, qf[s], st[f], 0, 0, 0);
                }

            // mask + row max (lane owns q = qlo + l31)
            const int qg = qlo + l31;
            const bool dm = (64 * kt + 63 > qlo);
            float tmax = -INFINITY;
            #pragma unroll
            for (int f = 0; f < 2; ++f)
                #pragma unroll
                for (int r = 0; r < 16; ++r) {
                    float sv = st[f][r];
                    if (dm) {
                        int kvg = 64 * kt + 32 * f + (r & 3) + 8 * (r >> 2) + 4 * h;
                        if (kvg > qg) sv = -INFINITY;
                    }
                    st[f][r] = sv;
                    tmax = fmaxf(tmax, sv);
                }
            tmax = fmaxf(tmax, __shfl_xor(tmax, 32));
            float ty = fmaxf(tmax * LOG2E, -3.0e38f);

            if (!__all(ty - m <= 8.0f)) {            // T13 defer-max
                float mn = fmaxf(m, ty);
                float sc = exp2f(m - mn);
                lsum *= sc;
                #pragma unroll
                for (int dt = 0; dt < 2; ++dt)
                    #pragma unroll
                    for (int r = 0; r < 16; ++r) o[dt][r] *= sc;
                m = mn;
            }

            // exp + sum (in place)
            #pragma unroll
            for (int f = 0; f < 2; ++f)
                #pragma unroll
                for (int r = 0; r < 16; ++r) {
                    float pv = exp2f(fmaf(st[f][r], LOG2E, -m));
                    st[f][r] = pv;
                    lsum += pv;
                }

            // per 16-kv block: build PA frag (cvt_pk + half-wave exchange), 2 PV MFMAs
            #pragma unroll
            for (int s4 = 0; s4 < 4; ++s4) {
                const int f = s4 >> 1, rb2 = 8 * (s4 & 1);
                unsigned A = cvtpk_bf16(st[f][rb2 + 0], st[f][rb2 + 1]);
                unsigned B = cvtpk_bf16(st[f][rb2 + 2], st[f][rb2 + 3]);
                unsigned C = cvtpk_bf16(st[f][rb2 + 4], st[f][rb2 + 5]);
                unsigned D = cvtpk_bf16(st[f][rb2 + 6], st[f][rb2 + 7]);
                unsigned Ax = (unsigned)__shfl_xor((int)A, 32);
                unsigned Bx = (unsigned)__shfl_xor((int)B, 32);
                unsigned Cx = (unsigned)__shfl_xor((int)C, 32);
                unsigned Dx = (unsigned)__shfl_xor((int)D, 32);
                union { unsigned wv[4]; bf16x8 v; } pu;
                pu.wv[0] = h ? Cx : A;
                pu.wv[1] = h ? Dx : B;
                pu.wv[2] = h ? C : Ax;
                pu.wv[3] = h ? D : Bx;
                #pragma unroll
                for (int dt = 0; dt < 2; ++dt) {
                    int row = 32 * dt + l31;
                    bf16x8 vf = *(const bf16x8*)&Vb[p][row * 64 + (((2 * s4 + h) ^ (row & 7)) * 8)];
                    o[dt] = __builtin_amdgcn_mfma_f32_32x32x16_bf16(vf, pu.v, o[dt], 0, 0, 0);
                }
            }
        }
    }

    // normalize and write out (coalesce via wave-local LDS bounce)
    float lt = lsum + __shfl_xor(lsum, 32);
    float inv = 1.0f / lt;

    __syncthreads();                                  // all waves done with Kb
    ushort* Ob = ((ushort*)Kb) + wq * 2048;           // [32 q][64 d] per wave
    #pragma unroll
    for (int dt = 0; dt < 2; ++dt)
        #pragma unroll
        for (int r = 0; r < 16; r += 2) {
            int d = 32 * dt + (r & 3) + 8 * (r >> 2) + 4 * h;
            unsigned wrd = cvtpk_bf16(o[dt][r] * inv, o[dt][r + 1] * inv);
            *(unsigned*)&Ob[l31 * 64 + (((d >> 3) ^ (l31 & 7)) * 8) + (d & 7)] = wrd;
        }
    asm volatile("s_waitcnt lgkmcnt(0)" ::: "memory");  // wave-local publish

    ushort* Cg = ctx + (size_t)bh * SEQ * HD + (size_t)qlo * HD;
    #pragma unroll
    for (int i = 0; i < 4; ++i) {
        int qq = l >> 1, c = (l & 1) * 4 + i;
        int4 vvv = *(const int4*)&Ob[qq * 64 + ((c ^ (qq & 7)) * 8)];
        *(int4*)&Cg[qq * 64 + c * 8] = vvv;
    }
}

// ---------------------------------------------------------------------------
extern "C" void kernel_launch(void* const* d_in, const int* in_sizes, int n_in,
                              void* d_out, int out_size, void* d_ws, size_t ws_size,
                              hipStream_t stream)
{
    (void)in_sizes; (void)n_in; (void)out_size; (void)ws_size;
    const float* x  = (const float*)d_in[0];
    const float* Wq = (const float*)d_in[1];
    const float* Wk = (const float*)d_in[2];
    const float* Wv = (const float*)d_in[3];
    const float* Wo = (const float*)d_in[4];
    const float* bo = (const float*)d_in[5];
    float* out = (float*)d_out;

    ushort* wsu  = (ushort*)d_ws;
    ushort* xb   = wsu;                      // 4M
    ushort* wqb  = wsu + 4194304;            // 1M each
    ushort* wkb  = wsu + 5242880;
    ushort* wvb  = wsu + 6291456;
    ushort* wob  = wsu + 7340032;
    ushort* qbuf = wsu + 8388608;            // 4M, [B,H,T,HD], pre-scaled 0.125
    ushort* kbuf = wsu + 12582912;           // 4M, [B,H,T,HD]
    ushort* vtb  = wsu + 16777216;           // 4M, [B,H,HD,T]  (V transposed)
    ushort* ctxb = wsu + 20971520;           // 4M, flat == [B*T, D]

    cast_x_k<<<2048, 256, 0, stream>>>(x, xb, MTOT * DIM / 4);
    cast_w_k<<<dim3(512, 4), 256, 0, stream>>>(Wq, Wk, Wv, Wo,
                                               wqb, wkb, wvb, wob, DIM * DIM / 4);

    dim3 gqkv(MTOT / 128, DIM / 128, 3);
    gemm_bf16<0><<<gqkv, 256, 0, stream>>>(xb, wqb, wkb, wvb,
                                           qbuf, kbuf, vtb, nullptr, nullptr);

    dim3 ga(16, 32);
    attn_mfma2<<<ga, 256, 0, stream>>>(qbuf, kbuf, vtb, ctxb);

    dim3 go(MTOT / 128, DIM / 128, 1);
    gemm_bf16<1><<<go, 256, 0, stream>>>(ctxb, wob, nullptr, nullptr,
                                         nullptr, nullptr, nullptr, bo, out);
}

// Round 4
// 185.028 us; speedup vs baseline: 9.3196x; 1.5225x over previous
//
#include <hip/hip_runtime.h>
#include <math.h>

#define BATCH 2
#define SEQ   2048
#define DIM   1024
#define NH    16
#define HD    64
#define MTOT  4096

typedef __attribute__((ext_vector_type(8)))  short bf16x8;
typedef __attribute__((ext_vector_type(4)))  float f32x4;
typedef __attribute__((ext_vector_type(16))) float f32x16;

__device__ __forceinline__ ushort f2bf(float f) {
    union { float f; unsigned u; } v; v.f = f;
    unsigned r = v.u + 0x7fffu + ((v.u >> 16) & 1u);
    return (ushort)(r >> 16);
}

__device__ __forceinline__ unsigned cvtpk_bf16(float lo, float hi) {
    unsigned r;
    asm("v_cvt_pk_bf16_f32 %0, %1, %2" : "=v"(r) : "v"(lo), "v"(hi));
    return r;
}

// ---------------------------------------------------------------------------
// casts
// ---------------------------------------------------------------------------
__global__ __launch_bounds__(256)
void cast_x_k(const float* __restrict__ s, ushort* __restrict__ d, int n4)
{
    for (int i = blockIdx.x * blockDim.x + threadIdx.x; i < n4;
         i += gridDim.x * blockDim.x) {
        float4 v = ((const float4*)s)[i];
        ushort4 o;
        o.x = f2bf(v.x); o.y = f2bf(v.y); o.z = f2bf(v.z); o.w = f2bf(v.w);
        ((ushort4*)d)[i] = o;
    }
}

__global__ __launch_bounds__(256)
void cast_w_k(const float* __restrict__ s0, const float* __restrict__ s1,
              const float* __restrict__ s2, const float* __restrict__ s3,
              ushort* __restrict__ d0, ushort* __restrict__ d1,
              ushort* __restrict__ d2, ushort* __restrict__ d3, int n4)
{
    const float* s = (blockIdx.y == 0) ? s0 : (blockIdx.y == 1) ? s1
                   : (blockIdx.y == 2) ? s2 : s3;
    ushort* d = (blockIdx.y == 0) ? d0 : (blockIdx.y == 1) ? d1
              : (blockIdx.y == 2) ? d2 : d3;
    for (int i = blockIdx.x * blockDim.x + threadIdx.x; i < n4;
         i += gridDim.x * blockDim.x) {
        float4 v = ((const float4*)s)[i];
        ushort4 o;
        o.x = f2bf(v.x); o.y = f2bf(v.y); o.z = f2bf(v.z); o.w = f2bf(v.w);
        ((ushort4*)d)[i] = o;
    }
}

// ---------------------------------------------------------------------------
// bf16 NT GEMM:  C = A(MxK) * W(NxK)^T, K = 1024. 128x128 tile, BK=64.
// Staging: global_load_lds (16B), double-buffered LDS, counted vmcnt(8)
// across raw s_barrier (T3/T4): loads for tile t+2 issued at end of iter t,
// waited at top of iter t+2 -> ~1 full K-step in flight, no vmcnt(0) drain.
// LDS swizzle preserved by pre-swizzling the GLOBAL source chunk
// ((l&7)^(l>>3) — lane-pure since rows advance by 8), linear LDS dest.
// MODE 0: bf16 scatter; z=0 -> Q*0.125 [B,H,T,HD]; z=1 -> K [B,H,T,HD];
//         z=2 -> V^T [B,H,HD,T].   MODE 1: fp32 [M,N] + bias.
// ---------------------------------------------------------------------------
template<int MODE>
__global__ __launch_bounds__(256)
void gemm_bf16(const ushort* __restrict__ A,
               const ushort* __restrict__ W0, const ushort* __restrict__ W1,
               const ushort* __restrict__ W2,
               ushort* __restrict__ D0, ushort* __restrict__ D1,
               ushort* __restrict__ D2,
               const float* __restrict__ bias, float* __restrict__ Fout)
{
    __shared__ __align__(16) ushort As[2][128 * 64];
    __shared__ __align__(16) ushort Bs[2][128 * 64];

    const int tid = threadIdx.x;
    const int w = tid >> 6, l = tid & 63;
    const int g = l >> 4, l15 = l & 15;
    const int wr = w >> 1, wc = w & 1;
    const int brow = blockIdx.x * 128, bcol = blockIdx.y * 128;

    const ushort* W = (MODE == 1) ? W0
                    : (blockIdx.z == 0 ? W0 : (blockIdx.z == 1 ? W1 : W2));
    ushort* Dst = (MODE == 1) ? (ushort*)0
                : (blockIdx.z == 0 ? D0 : (blockIdx.z == 1 ? D1 : D2));

    // staging geometry: wave w stages A/B rows [32w, 32w+32), 4 issues each.
    const int rsub = l >> 3;                       // row-within-8 == row&7
    const int gc   = ((l & 7) ^ rsub) * 8;         // pre-swizzled col chunk
    const size_t arow0 = (size_t)(brow + 32 * w + rsub) * DIM;
    const size_t brow0 = (size_t)(bcol + 32 * w + rsub) * DIM;

    auto STAGE = [&](int buf, int ktel) {
        #pragma unroll
        for (int i = 0; i < 4; ++i) {
            __builtin_amdgcn_global_load_lds(
                (const __attribute__((address_space(1))) void*)
                    &A[arow0 + (size_t)(8 * i) * DIM + ktel + gc],
                (__attribute__((address_space(3))) void*)
                    &As[buf][(32 * w + 8 * i) * 64], 16, 0, 0);
            __builtin_amdgcn_global_load_lds(
                (const __attribute__((address_space(1))) void*)
                    &W[brow0 + (size_t)(8 * i) * DIM + ktel + gc],
                (__attribute__((address_space(3))) void*)
                    &Bs[buf][(32 * w + 8 * i) * 64], 16, 0, 0);
        }
    };

    STAGE(0, 0);
    STAGE(1, 64);

    f32x4 acc[4][4] = {};

    for (int t = 0; t < 16; ++t) {
        const int cur = t & 1;
        if (t < 15) asm volatile("s_waitcnt vmcnt(8)" ::: "memory");
        else        asm volatile("s_waitcnt vmcnt(0)" ::: "memory");
        __builtin_amdgcn_s_barrier();
        __builtin_amdgcn_sched_barrier(0);

        #pragma unroll
        for (int kh = 0; kh < 2; ++kh) {
            bf16x8 af[4], bfr[4];
            #pragma unroll
            for (int mi = 0; mi < 4; ++mi) {
                int row = 64 * wr + 16 * mi + l15;
                af[mi] = *(const bf16x8*)&As[cur][row * 64 + (((4 * kh + g) ^ (row & 7)) * 8)];
            }
            #pragma unroll
            for (int nj = 0; nj < 4; ++nj) {
                int row = 64 * wc + 16 * nj + l15;
                bfr[nj] = *(const bf16x8*)&Bs[cur][row * 64 + (((4 * kh + g) ^ (row & 7)) * 8)];
            }
            __builtin_amdgcn_s_setprio(1);
            #pragma unroll
            for (int mi = 0; mi < 4; ++mi)
                #pragma unroll
                for (int nj = 0; nj < 4; ++nj)
                    acc[mi][nj] = __builtin_amdgcn_mfma_f32_16x16x32_bf16(
                        af[mi], bfr[nj], acc[mi][nj], 0, 0, 0);
            __builtin_amdgcn_s_setprio(0);
        }

        __builtin_amdgcn_sched_barrier(0);
        __builtin_amdgcn_s_barrier();
        if (t + 2 < 16) STAGE(cur, (t + 2) * 64);
    }

    if (MODE == 0) {
        const float osc = (blockIdx.z == 0) ? 0.125f : 1.0f;
        if (blockIdx.z == 2) {
            #pragma unroll
            for (int mi = 0; mi < 4; ++mi)
                #pragma unroll
                for (int nj = 0; nj < 4; ++nj)
                    #pragma unroll
                    for (int reg = 0; reg < 4; ++reg) {
                        int row = brow + 64 * wr + 16 * mi + 4 * g + reg;
                        int col = bcol + 64 * wc + 16 * nj + l15;
                        int b = row >> 11, t = row & (SEQ - 1);
                        int hh = col >> 6, hd = col & 63;
                        Dst[((size_t)(b * NH + hh) * HD + hd) * SEQ + t] =
                            f2bf(acc[mi][nj][reg]);
                    }
        } else {
            #pragma unroll
            for (int mi = 0; mi < 4; ++mi)
                #pragma unroll
                for (int nj = 0; nj < 4; ++nj)
                    #pragma unroll
                    for (int reg = 0; reg < 4; ++reg) {
                        int row = brow + 64 * wr + 16 * mi + 4 * g + reg;
                        int col = bcol + 64 * wc + 16 * nj + l15;
                        int b = row >> 11, t = row & (SEQ - 1);
                        int hh = col >> 6, hd = col & 63;
                        Dst[((size_t)(b * NH + hh) * SEQ + t) * HD + hd] =
                            f2bf(acc[mi][nj][reg] * osc);
                    }
        }
    } else {
        #pragma unroll
        for (int nj = 0; nj < 4; ++nj) {
            int col = bcol + 64 * wc + 16 * nj + l15;
            float bv = bias[col];
            #pragma unroll
            for (int mi = 0; mi < 4; ++mi)
                #pragma unroll
                for (int reg = 0; reg < 4; ++reg) {
                    int row = brow + 64 * wr + 16 * mi + 4 * g + reg;
                    Fout[(size_t)row * DIM + col] = acc[mi][nj][reg] + bv;
                }
        }
    }
}

// ---------------------------------------------------------------------------
// Swapped-QK^T MFMA flash attention (causal), 32x32x16.  (unchanged, R2)
// ---------------------------------------------------------------------------
__global__ __launch_bounds__(256, 2)
void attn_mfma2(const ushort* __restrict__ q, const ushort* __restrict__ k,
                const ushort* __restrict__ vt, ushort* __restrict__ ctx)
{
    __shared__ __align__(16) ushort Kb[2][4096];
    __shared__ __align__(16) ushort Vb[2][4096];

    const int tid = threadIdx.x;
    const int wq = tid >> 6, l = tid & 63;
    const int l31 = l & 31, h = l >> 5;
    const int y = blockIdx.y;
    const int qt = (y & 16) ? (15 - (int)blockIdx.x) : (int)blockIdx.x;
    const int bh = y;
    const int qlo = qt * 128 + wq * 32;
    const int ktmax = 2 * qt + 1;
    const float LOG2E = 1.44269504f;

    const ushort* Qg = q  + (size_t)bh * SEQ * HD;
    const ushort* Kg = k  + (size_t)bh * SEQ * HD;
    const ushort* Vg = vt + (size_t)bh * HD * SEQ;

    bf16x8 qf[4];
    #pragma unroll
    for (int s = 0; s < 4; ++s)
        qf[s] = *(const bf16x8*)&Qg[(size_t)(qlo + l31) * HD + 16 * s + 8 * h];

    int4 rk[2], rv[2];
    #pragma unroll
    for (int i = 0; i < 2; ++i) {
        int idx = tid + 256 * i;
        int row = idx >> 3, c = idx & 7;
        rk[i] = *(const int4*)&Kg[(size_t)row * HD + c * 8];
        rv[i] = *(const int4*)&Vg[(size_t)row * SEQ + c * 8];
    }

    f32x16 o[2] = {};
    float m = -3.0e38f, lsum = 0.f;

    for (int kt = 0; kt <= ktmax; ++kt) {
        const int p = kt & 1;
        __syncthreads();
        #pragma unroll
        for (int i = 0; i < 2; ++i) {
            int idx = tid + 256 * i;
            int row = idx >> 3, c = idx & 7;
            *(int4*)&Kb[p][row * 64 + ((c ^ (row & 7)) * 8)] = rk[i];
            *(int4*)&Vb[p][row * 64 + ((c ^ (row & 7)) * 8)] = rv[i];
        }
        __syncthreads();
        if (kt < ktmax) {
            #pragma unroll
            for (int i = 0; i < 2; ++i) {
                int idx = tid + 256 * i;
                int row = idx >> 3, c = idx & 7;
                rk[i] = *(const int4*)&Kg[(size_t)(64 * (kt + 1) + row) * HD + c * 8];
                rv[i] = *(const int4*)&Vg[(size_t)row * SEQ + 64 * (kt + 1) + c * 8];
            }
        }

        if (64 * kt < qlo + 32) {
            f32x16 st[2] = {};
            #pragma unroll
            for (int s = 0; s < 4; ++s)
                #pragma unroll
                for (int f = 0; f < 2; ++f) {
                    int row = 32 * f + l31;
                    bf16x8 kf = *(const bf16x8*)&Kb[p][row * 64 + (((2 * s + h) ^ (row & 7)) * 8)];
                    st[f] = __builtin_amdgcn_mfma_f32_32x32x16_bf16(kf, qf[s], st[f], 0, 0, 0);
                }

            const int qg = qlo + l31;
            const bool dm = (64 * kt + 63 > qlo);
            float tmax = -INFINITY;
            #pragma unroll
            for (int f = 0; f < 2; ++f)
                #pragma unroll
                for (int r = 0; r < 16; ++r) {
                    float sv = st[f][r];
                    if (dm) {
                        int kvg = 64 * kt + 32 * f + (r & 3) + 8 * (r >> 2) + 4 * h;
                        if (kvg > qg) sv = -INFINITY;
                    }
                    st[f][r] = sv;
                    tmax = fmaxf(tmax, sv);
                }
            tmax = fmaxf(tmax, __shfl_xor(tmax, 32));
            float ty = fmaxf(tmax * LOG2E, -3.0e38f);

            if (!__all(ty - m <= 8.0f)) {
                float mn = fmaxf(m, ty);
                float sc = exp2f(m - mn);
                lsum *= sc;
                #pragma unroll
                for (int dt = 0; dt < 2; ++dt)
                    #pragma unroll
                    for (int r = 0; r < 16; ++r) o[dt][r] *= sc;
                m = mn;
            }

            #pragma unroll
            for (int f = 0; f < 2; ++f)
                #pragma unroll
                for (int r = 0; r < 16; ++r) {
                    float pv = exp2f(fmaf(st[f][r], LOG2E, -m));
                    st[f][r] = pv;
                    lsum += pv;
                }

            #pragma unroll
            for (int s4 = 0; s4 < 4; ++s4) {
                const int f = s4 >> 1, rb2 = 8 * (s4 & 1);
                unsigned Aa = cvtpk_bf16(st[f][rb2 + 0], st[f][rb2 + 1]);
                unsigned Bb = cvtpk_bf16(st[f][rb2 + 2], st[f][rb2 + 3]);
                unsigned Cc = cvtpk_bf16(st[f][rb2 + 4], st[f][rb2 + 5]);
                unsigned Dd = cvtpk_bf16(st[f][rb2 + 6], st[f][rb2 + 7]);
                unsigned Ax = (unsigned)__shfl_xor((int)Aa, 32);
                unsigned Bx = (unsigned)__shfl_xor((int)Bb, 32);
                unsigned Cx = (unsigned)__shfl_xor((int)Cc, 32);
                unsigned Dx = (unsigned)__shfl_xor((int)Dd, 32);
                union { unsigned wv[4]; bf16x8 v; } pu;
                pu.wv[0] = h ? Cx : Aa;
                pu.wv[1] = h ? Dx : Bb;
                pu.wv[2] = h ? Cc : Ax;
                pu.wv[3] = h ? Dd : Bx;
                #pragma unroll
                for (int dt = 0; dt < 2; ++dt) {
                    int row = 32 * dt + l31;
                    bf16x8 vf = *(const bf16x8*)&Vb[p][row * 64 + (((2 * s4 + h) ^ (row & 7)) * 8)];
                    o[dt] = __builtin_amdgcn_mfma_f32_32x32x16_bf16(vf, pu.v, o[dt], 0, 0, 0);
                }
            }
        }
    }

    float lt = lsum + __shfl_xor(lsum, 32);
    float inv = 1.0f / lt;

    __syncthreads();
    ushort* Ob = ((ushort*)Kb) + wq * 2048;
    #pragma unroll
    for (int dt = 0; dt < 2; ++dt)
        #pragma unroll
        for (int r = 0; r < 16; r += 2) {
            int d = 32 * dt + (r & 3) + 8 * (r >> 2) + 4 * h;
            unsigned wrd = cvtpk_bf16(o[dt][r] * inv, o[dt][r + 1] * inv);
            *(unsigned*)&Ob[l31 * 64 + (((d >> 3) ^ (l31 & 7)) * 8) + (d & 7)] = wrd;
        }
    asm volatile("s_waitcnt lgkmcnt(0)" ::: "memory");

    ushort* Cg = ctx + (size_t)bh * SEQ * HD + (size_t)qlo * HD;
    #pragma unroll
    for (int i = 0; i < 4; ++i) {
        int qq = l >> 1, c = (l & 1) * 4 + i;
        int4 vvv = *(const int4*)&Ob[qq * 64 + ((c ^ (qq & 7)) * 8)];
        *(int4*)&Cg[qq * 64 + c * 8] = vvv;
    }
}

// ---------------------------------------------------------------------------
extern "C" void kernel_launch(void* const* d_in, const int* in_sizes, int n_in,
                              void* d_out, int out_size, void* d_ws, size_t ws_size,
                              hipStream_t stream)
{
    (void)in_sizes; (void)n_in; (void)out_size; (void)ws_size;
    const float* x  = (const float*)d_in[0];
    const float* Wq = (const float*)d_in[1];
    const float* Wk = (const float*)d_in[2];
    const float* Wv = (const float*)d_in[3];
    const float* Wo = (const float*)d_in[4];
    const float* bo = (const float*)d_in[5];
    float* out = (float*)d_out;

    ushort* wsu  = (ushort*)d_ws;
    ushort* xb   = wsu;                      // 4M
    ushort* wqb  = wsu + 4194304;            // 1M each
    ushort* wkb  = wsu + 5242880;
    ushort* wvb  = wsu + 6291456;
    ushort* wob  = wsu + 7340032;
    ushort* qbuf = wsu + 8388608;            // 4M, [B,H,T,HD], pre-scaled 0.125
    ushort* kbuf = wsu + 12582912;           // 4M, [B,H,T,HD]
    ushort* vtb  = wsu + 16777216;           // 4M, [B,H,HD,T]  (V transposed)
    ushort* ctxb = wsu + 20971520;           // 4M, flat == [B*T, D]

    cast_x_k<<<2048, 256, 0, stream>>>(x, xb, MTOT * DIM / 4);
    cast_w_k<<<dim3(512, 4), 256, 0, stream>>>(Wq, Wk, Wv, Wo,
                                               wqb, wkb, wvb, wob, DIM * DIM / 4);

    dim3 gqkv(MTOT / 128, DIM / 128, 3);
    gemm_bf16<0><<<gqkv, 256, 0, stream>>>(xb, wqb, wkb, wvb,
                                           qbuf, kbuf, vtb, nullptr, nullptr);

    dim3 ga(16, 32);
    attn_mfma2<<<ga, 256, 0, stream>>>(qbuf, kbuf, vtb, ctxb);

    dim3 go(MTOT / 128, DIM / 128, 1);
    gemm_bf16<1><<<go, 256, 0, stream>>>(ctxb, wob, nullptr, nullptr,
                                         nullptr, nullptr, nullptr, bo, out);
}